// Round 3
// baseline (1679.476 us; speedup 1.0000x reference)
//
#include <hip/hip_runtime.h>
#include <hip/hip_bf16.h>

// Problem constants (from reference): B=4, T=512, H=2048, V=32000
#define B_ 4
#define T_ 512
#define H_ 2048
#define V_ 32000
#define M_ (B_ * T_)          // 2048 tokens
#define BETA_ 0.1f

// GEMM tiling: 128x128 block tile, BK=32, 256 threads (4 waves, each 64x64)
#define BM 128
#define BN 128
#define BK 32
#define NTILES (V_ / BN)      // 250 n-tiles
#define NP (NTILES * 2)       // 500 partials per row (per-64-col-wave slab)
#define NPAD 512              // padded row length for [m][p] partial layout
#define GRID_LIN 4096

typedef __attribute__((ext_vector_type(8))) short short8;  // 8 bf16 = 4 VGPRs
typedef __attribute__((ext_vector_type(4))) float f32x4;   // MFMA accumulator

__device__ __forceinline__ void async_copy16(const void* g, void* l) {
  __builtin_amdgcn_global_load_lds(
      (const __attribute__((address_space(1))) void*)g,
      (__attribute__((address_space(3))) void*)l, 16, 0, 0);
}

__device__ __forceinline__ unsigned short f2bf(float f) {
  unsigned int u = __float_as_uint(f);
  u += 0x7fffu + ((u >> 16) & 1u);
  return (unsigned short)(u >> 16);
}

// Fused convert: first n4a groups from inA->outA (weights), rest inB->outB (x).
__global__ void cvt2_bf16_kernel(const float* __restrict__ inA,
                                 unsigned short* __restrict__ outA, int n4a,
                                 const float* __restrict__ inB,
                                 unsigned short* __restrict__ outB, int n4b) {
  int i = blockIdx.x * blockDim.x + threadIdx.x;
  const float* in; unsigned short* out;
  if (i < n4a) { in = inA; out = outA; }
  else { i -= n4a; if (i >= n4b) return; in = inB; out = outB; }
  float4 v = ((const float4*)in)[i];
  ushort4 o;
  o.x = f2bf(v.x); o.y = f2bf(v.y); o.z = f2bf(v.z); o.w = f2bf(v.w);
  ((ushort4*)out)[i] = o;
}

// Selected logit: exact fp32 dot(x[m,:], W[ids[m],:]). One wave per (model, token).
__global__ void sel_kernel(const float* __restrict__ x, const float* __restrict__ w,
                           const float* __restrict__ rx, const float* __restrict__ rw,
                           const int* __restrict__ ids, float* __restrict__ sel) {
  int gw = (blockIdx.x * 256 + threadIdx.x) >> 6;  // global wave id, 0..4095
  int l = threadIdx.x & 63;
  int md = gw >> 11;          // model: 0 = policy, 1 = ref
  int m = gw & (M_ - 1);      // token
  const float* xr = (md ? rx : x) + (size_t)m * H_;
  const float* wr = (md ? rw : w) + (size_t)ids[m] * H_;
  float s = 0.0f;
#pragma unroll
  for (int it = 0; it < H_ / 256; ++it) {
    int k = it * 256 + l * 4;
    float4 a = *(const float4*)(xr + k);
    float4 b = *(const float4*)(wr + k);
    s += a.x * b.x + a.y * b.y + a.z * b.z + a.w * b.w;
  }
#pragma unroll
  for (int off = 32; off; off >>= 1) s += __shfl_xor(s, off, 64);
  if (l == 0) sel[md * M_ + m] = s;
}

// Fused bf16 MFMA GEMM (logits = A * Bw^T) + per-row online (max, sumexp).
// Distance-2 pipelined K-loop: double-buffered LDS, global_load_lds for tile
// k+2 issued each iter, raw s_waitcnt vmcnt(4) + s_barrier (never vmcnt(0))
// so HBM staging latency (~900 cyc, B streams cold) is hidden by the pipeline
// depth instead of occupancy.
__global__ __launch_bounds__(256) void gemm_lse_kernel(
    const unsigned short* __restrict__ A,    // [M_][H_] bf16
    const unsigned short* __restrict__ Bw,   // [V_][H_] bf16
    float* __restrict__ pmax,                // [M_][NPAD]
    float* __restrict__ psum) {              // [M_][NPAD]
  const int linear = blockIdx.x;
  const int nt = (linear & 7) + 8 * (linear >> 7);   // n-tile, xcd-grouped
  if (nt >= NTILES) return;
  const int mb = (linear >> 3) & 15;                 // m-block

  __shared__ char smem[32768];              // 2 x (A 8KB + B 8KB)
  char* As0 = smem;          char* As1 = smem + 8192;
  char* Bs0 = smem + 16384;  char* Bs1 = smem + 24576;

  const int tid = threadIdx.x;
  const int w = tid >> 6, l = tid & 63;
  const int quad = l >> 4, lr = l & 15;
  const int m0 = mb * BM, n0 = nt * BN;
  const int wm = (w >> 1) * 64, wn = (w & 1) * 64;

  // Staging: 512 slots per matrix, 2 per thread. Slot s: kb = s>>7, row = s&127.
  const int s0 = tid, s1 = tid + 256;
  const int o0 = s0 * 16, o1 = s1 * 16;
  const unsigned short* gA0 = A + (size_t)(m0 + (s0 & 127)) * H_ + (s0 >> 7) * 8;
  const unsigned short* gA1 = A + (size_t)(m0 + (s1 & 127)) * H_ + (s1 >> 7) * 8;
  const unsigned short* gB0 = Bw + (size_t)(n0 + (s0 & 127)) * H_ + (s0 >> 7) * 8;
  const unsigned short* gB1 = Bw + (size_t)(n0 + (s1 & 127)) * H_ + (s1 >> 7) * 8;

  // Prologue: stage tile 0 -> buf0, tile 1 -> buf1 (8 loads in flight).
  async_copy16(gA0, As0 + o0); async_copy16(gA1, As0 + o1);
  async_copy16(gB0, Bs0 + o0); async_copy16(gB1, Bs0 + o1);
  gA0 += BK; gA1 += BK; gB0 += BK; gB1 += BK;
  async_copy16(gA0, As1 + o0); async_copy16(gA1, As1 + o1);
  async_copy16(gB0, Bs1 + o0); async_copy16(gB1, Bs1 + o1);
  gA0 += BK; gA1 += BK; gB0 += BK; gB1 += BK;

  f32x4 acc[4][4] = {};

  int aOff[4], bOff[4];
#pragma unroll
  for (int i = 0; i < 4; ++i) {
    aOff[i] = (quad * 128 + wm + i * 16 + lr) * 16;
    bOff[i] = (quad * 128 + wn + i * 16 + lr) * 16;
  }

  // One pipelined K-iteration. VMSTR: "4" = wait tile-k loads only (k+1's 4
  // stay in flight); lgkmcnt(0)+barrier protects the buffer before overwrite.
#define KITER(VMSTR, PRE, AS, BS)                                              \
  {                                                                            \
    asm volatile("s_waitcnt vmcnt(" VMSTR ")\n\ts_barrier" ::: "memory");      \
    short8 af[4], bf[4];                                                       \
    _Pragma("unroll") for (int i = 0; i < 4; ++i)                              \
        af[i] = *(const short8*)(AS + aOff[i]);                                \
    _Pragma("unroll") for (int j = 0; j < 4; ++j)                              \
        bf[j] = *(const short8*)(BS + bOff[j]);                                \
    asm volatile("s_waitcnt lgkmcnt(0)\n\ts_barrier" ::: "memory");            \
    if (PRE) {                                                                 \
      async_copy16(gA0, AS + o0); async_copy16(gA1, AS + o1);                  \
      async_copy16(gB0, BS + o0); async_copy16(gB1, BS + o1);                  \
      gA0 += BK; gA1 += BK; gB0 += BK; gB1 += BK;                              \
    }                                                                          \
    _Pragma("unroll") for (int i = 0; i < 4; ++i)                              \
    _Pragma("unroll") for (int j = 0; j < 4; ++j)                              \
      acc[i][j] = __builtin_amdgcn_mfma_f32_16x16x32_bf16(af[i], bf[j],        \
                                                          acc[i][j], 0, 0, 0); \
  }

  // kt = 0..61 prefetch tiles 2..63; kt = 62, 63 drain.
  for (int kp = 0; kp < 31; ++kp) {
    KITER("4", 1, As0, Bs0);
    KITER("4", 1, As1, Bs1);
  }
  KITER("4", 0, As0, Bs0);   // kt = 62
  KITER("0", 0, As1, Bs1);   // kt = 63
#undef KITER

  // Epilogue: C/D layout col = lane&15 (n), row = quad*4 + reg.
  const int p_idx = nt * 2 + (w & 1);
#pragma unroll
  for (int i = 0; i < 4; ++i) {
#pragma unroll
    for (int r = 0; r < 4; ++r) {
      float vmax = fmaxf(fmaxf(acc[i][0][r], acc[i][1][r]),
                         fmaxf(acc[i][2][r], acc[i][3][r]));
#pragma unroll
      for (int off = 8; off; off >>= 1) vmax = fmaxf(vmax, __shfl_xor(vmax, off, 64));
      float s = __expf(acc[i][0][r] - vmax) + __expf(acc[i][1][r] - vmax) +
                __expf(acc[i][2][r] - vmax) + __expf(acc[i][3][r] - vmax);
#pragma unroll
      for (int off = 8; off; off >>= 1) s += __shfl_xor(s, off, 64);
      if (lr == 0) {
        int mg = m0 + wm + i * 16 + quad * 4 + r;
        pmax[(size_t)mg * NPAD + p_idx] = vmax;
        psum[(size_t)mg * NPAD + p_idx] = s;
      }
    }
  }
}

// One wave per (model, token): coalesced read of the token's 500 partials.
__global__ void lse_merge_kernel(
    const float* __restrict__ pmaxP, const float* __restrict__ psumP,
    const float* __restrict__ pmaxR, const float* __restrict__ psumR,
    const float* __restrict__ sel, float* __restrict__ lp) {
  int gw = (blockIdx.x * 256 + threadIdx.x) >> 6;  // 0..4095
  int l = threadIdx.x & 63;
  int md = gw >> 11, m = gw & (M_ - 1);
  const float* pm = (md ? pmaxR : pmaxP) + (size_t)m * NPAD;
  const float* ps = (md ? psumR : psumP) + (size_t)m * NPAD;
  float mx = -3.0e38f, s = 0.0f;
  for (int p = l; p < NP; p += 64) {
    float a = pm[p], b = ps[p];
    float nm = fmaxf(mx, a);
    s = s * __expf(mx - nm) + b * __expf(a - nm);
    mx = nm;
  }
#pragma unroll
  for (int off = 32; off; off >>= 1) {
    float omx = __shfl_xor(mx, off, 64);
    float os  = __shfl_xor(s, off, 64);
    float nm = fmaxf(mx, omx);
    s = s * __expf(mx - nm) + os * __expf(omx - nm);
    mx = nm;
  }
  if (l == 0) lp[md * M_ + m] = sel[md * M_ + m] - (mx + __logf(s));
}

// Single block: coef1=coef2=1 exactly, loss = mean(-adv + BETA*kl).
__global__ void loss_kernel(const float* __restrict__ lp,
                            const float* __restrict__ adv,
                            const int* __restrict__ mask,
                            float* __restrict__ out) {
  __shared__ float sp[16], sm[16];
  int t = threadIdx.x;
  float pt = 0.0f, mk = 0.0f;
  for (int m = t; m < M_; m += 1024) {
    float d = lp[M_ + m] - lp[m];       // ref_logp - logp
    float kl = __expf(d) - d - 1.0f;
    float mkm = (float)mask[m];
    pt += (-adv[m >> 9] + BETA_ * kl) * mkm;
    mk += mkm;
  }
#pragma unroll
  for (int off = 32; off; off >>= 1) {
    pt += __shfl_xor(pt, off, 64);
    mk += __shfl_xor(mk, off, 64);
  }
  int wv = t >> 6, l = t & 63;
  if (l == 0) { sp[wv] = pt; sm[wv] = mk; }
  __syncthreads();
  if (t == 0) {
    float a = 0.0f, b = 0.0f;
#pragma unroll
    for (int i = 0; i < 16; ++i) { a += sp[i]; b += sm[i]; }
    out[0] = a / fmaxf(b, 1.0f);
  }
}

extern "C" void kernel_launch(void* const* d_in, const int* in_sizes, int n_in,
                              void* d_out, int out_size, void* d_ws, size_t ws_size,
                              hipStream_t stream) {
  const float* x    = (const float*)d_in[0];
  const float* lw   = (const float*)d_in[1];
  const float* rx   = (const float*)d_in[2];
  const float* rw   = (const float*)d_in[3];
  const float* adv  = (const float*)d_in[4];
  const int*   ids  = (const int*)d_in[5];
  const int*   mask = (const int*)d_in[6];
  float* out = (float*)d_out;

  // Workspace: Wb (bf16) | xb (bf16) | pmaxP|psumP|pmaxR|psumR ([M_][NPAD] f32)
  // | sel [2][M_] | lp [2][M_]   (~156.3 MB)
  char* ws = (char*)d_ws;
  unsigned short* Wb = (unsigned short*)ws;
  unsigned short* xb = (unsigned short*)(ws + (size_t)V_ * H_ * 2);
  char* p0 = ws + (size_t)V_ * H_ * 2 + (size_t)M_ * H_ * 2;
  const size_t PSZ = (size_t)M_ * NPAD * 4;
  float* pmaxP = (float*)(p0);
  float* psumP = (float*)(p0 + 1 * PSZ);
  float* pmaxR = (float*)(p0 + 2 * PSZ);
  float* psumR = (float*)(p0 + 3 * PSZ);
  float* sel   = (float*)(p0 + 4 * PSZ);
  float* lp    = (float*)(p0 + 4 * PSZ + 2 * M_ * 4);

  const int n4x = M_ * H_ / 4, n4w = V_ * H_ / 4;
  const int cvtg = (n4w + n4x + 255) / 256;

  // Policy model
  cvt2_bf16_kernel<<<cvtg, 256, 0, stream>>>(lw, Wb, n4w, x, xb, n4x);
  sel_kernel<<<(2 * M_) / 4, 256, 0, stream>>>(x, lw, rx, rw, ids, sel);
  gemm_lse_kernel<<<GRID_LIN, 256, 0, stream>>>(xb, Wb, pmaxP, psumP);
  // Ref model (reuse bf16 buffers — stream-ordered)
  cvt2_bf16_kernel<<<cvtg, 256, 0, stream>>>(rw, Wb, n4w, rx, xb, n4x);
  gemm_lse_kernel<<<GRID_LIN, 256, 0, stream>>>(xb, Wb, pmaxR, psumR);

  lse_merge_kernel<<<(2 * M_) / 4, 256, 0, stream>>>(pmaxP, psumP, pmaxR, psumR,
                                                     sel, lp);
  loss_kernel<<<1, 1024, 0, stream>>>(lp, adv, mask, out);
}